// Round 4
// baseline (1701.102 us; speedup 1.0000x reference)
//
#include <hip/hip_runtime.h>

// LSTM_77893526880768: B=T=F=H=256.  256 independent row-chains, 255 steps.
//
// v13 = v12 (intra-WG recurrence, weights CU-resident) + CLOCK experiment.
//
// Evidence ladder:
//   v9  (64 WG, cross-WG flags+barrier): 4.78us/step
//   v10 (barrier-free wave flags):       5.14us/step
//   v11 (2 chains/WG, latency overlap):  9.39us/step (2x phase, NO overlap)
//   v12 (16 WG, zero cross-WG sync):     5.24us/step
//   => protocol structure is irrelevant; the invariant cost is elsewhere.
// Counter arithmetic on v12 (scaled to the 16 active CUs): VALUBusy 41%
// with ~390 VALU instr/thread/step -> step ~3900cy -> clock ~750 MHz.
// MFMA arithmetic independently gives ~720 MHz (and ~750 from v9's counters).
// At 2.4 GHz the same counters would require ~6x more instructions than the
// loop body contains.  THEORY: SMU holds ~750 MHz at 6% CU occupancy; every
// version paid a ~3.2x clock penalty.
//
// v13 tests this directly:
//   - grid 256 blocks: blocks 0..15 = the v12 recurrence (unchanged math),
//     blocks 16..255 = HEATERS: low-power dependent-rcp spin until the 16
//     real WGs post done-count==16 (system-scope RMW).  One polling wave per
//     heater block (system atomic every ~500cy), other waves spin on an LDS
//     mailbox -- avoids IC contention.  Same kernel => same 144KB LDS =>
//     exactly 1 block/CU chip-wide, heaters never share a CU's pipes with a
//     recurrent block.
//   - P prefetch ONE STEP AHEAD (pvA/pvB named double-buffer, pair-unrolled
//     t-loop for static indexing): EW no longer waits on HBM/L3 latency.
//
// Workspace layout:
//   [0, 256)        done int (memset 0 AFTER precompute, which reads WxT)
//   [0, 512K)       WxT bf16   (dead after precompute)
//   [512K, 1M)      WhT bf16
//   [1M, 1M+4K)     bcat fp32
//   [1M+4K, ...)    P bf16  [t][rg16][n][16] = 133,693,440 B

#define STEPS 255

typedef short bf16x8 __attribute__((ext_vector_type(8)));
typedef short bf16x4 __attribute__((ext_vector_type(4)));
typedef float f32x4  __attribute__((ext_vector_type(4)));

__device__ inline unsigned short f2bf(float f) {
  unsigned int u = __float_as_uint(f);
  unsigned int r = (u + 0x7FFFu + ((u >> 16) & 1u)) >> 16;  // RNE
  return (unsigned short)r;
}
__device__ inline float bf2f(unsigned short s) {
  return __uint_as_float(((unsigned int)s) << 16);
}
__device__ inline float sig_f(float x) {
  float e = exp2f(-1.442695041f * x);
  return __builtin_amdgcn_rcpf(1.0f + e);
}
__device__ inline float tanh_f(float x) {
  float e = exp2f(-2.885390082f * x);
  return 2.0f * __builtin_amdgcn_rcpf(1.0f + e) - 1.0f;
}

// ---------- prep: W transpose (W[k][j] fp32 -> WT[g*256+j][k] bf16) ----------
__global__ __launch_bounds__(256) void lstm_prep_w(
    const float* __restrict__ m0, const float* __restrict__ m1,
    const float* __restrict__ m2, const float* __restrict__ m3,
    const float* __restrict__ m4, const float* __restrict__ m5,
    const float* __restrict__ m6, const float* __restrict__ m7,
    unsigned short* __restrict__ WxT, unsigned short* __restrict__ WhT) {
  const float* mats[8] = {m0, m1, m2, m3, m4, m5, m6, m7};
  int mat = blockIdx.z;
  const float* W = mats[mat];
  unsigned short* out = (mat < 4 ? WxT : WhT) + (size_t)(mat & 3) * 256 * 256;
  int kblk = blockIdx.x * 32, jblk = blockIdx.y * 32;
  __shared__ float tile[32][33];
  int tx = threadIdx.x & 31, ty = threadIdx.x >> 5;
#pragma unroll
  for (int i = 0; i < 4; ++i) {
    int kk = ty + i * 8;
    tile[kk][tx] = W[(size_t)(kblk + kk) * 256 + jblk + tx];
  }
  __syncthreads();
#pragma unroll
  for (int i = 0; i < 4; ++i) {
    int jj = ty + i * 8;
    out[(size_t)(jblk + jj) * 256 + kblk + tx] = f2bf(tile[tx][jj]);
  }
}

// ---------- prep: bias fold ----------
__global__ void lstm_prep_b(
    const float* __restrict__ bx0, const float* __restrict__ bx1,
    const float* __restrict__ bx2, const float* __restrict__ bx3,
    const float* __restrict__ bh0, const float* __restrict__ bh1,
    const float* __restrict__ bh2, const float* __restrict__ bh3,
    float* __restrict__ bcat) {
  const float* bx[4] = {bx0, bx1, bx2, bx3};
  const float* bh[4] = {bh0, bh1, bh2, bh3};
  int i = blockIdx.x * 256 + threadIdx.x;
  int g = i >> 8, j = i & 255;
  bcat[i] = bx[g][j] + bh[g][j];
}

// ---------- precompute: P[t][rg16][n][rl] = bcat[n] + sum_k x[r,t,k] Wx[k,n] ----------
// grid (255, 2): blockIdx.y selects 8 of the 16 n-blocks (x-frags duplicated).
__global__ __launch_bounds__(256, 1) void lstm_precompute(
    const float* __restrict__ x, const unsigned short* __restrict__ WxT,
    const float* __restrict__ bcat, unsigned short* __restrict__ P) {
  int t = blockIdx.x;
  int tid = threadIdx.x;
  int w = tid >> 6, lane = tid & 63, q = lane >> 4, cl = lane & 15;
  int rbase = w * 64;

  bf16x8 bfrag[8][4];
#pragma unroll
  for (int kt = 0; kt < 8; ++kt) {
    int k0 = kt * 32 + q * 8;
#pragma unroll
    for (int rt = 0; rt < 4; ++rt) {
      const float* xp = x + (((size_t)(rbase + rt * 16 + cl) * 256 + t) * 256 + k0);
      f32x4 lo = *(const f32x4*)xp;
      f32x4 hi = *(const f32x4*)(xp + 4);
      bf16x8 bv;
      bv[0] = (short)f2bf(lo[0]); bv[1] = (short)f2bf(lo[1]);
      bv[2] = (short)f2bf(lo[2]); bv[3] = (short)f2bf(lo[3]);
      bv[4] = (short)f2bf(hi[0]); bv[5] = (short)f2bf(hi[1]);
      bv[6] = (short)f2bf(hi[2]); bv[7] = (short)f2bf(hi[3]);
      bfrag[kt][rt] = bv;
    }
  }

  for (int nbi = 0; nbi < 8; ++nbi) {
    int nblk = (blockIdx.y * 8 + nbi) * 64;
    f32x4 acc[4][4];
#pragma unroll
    for (int a = 0; a < 4; ++a)
#pragma unroll
      for (int b = 0; b < 4; ++b) acc[a][b] = f32x4{0.f, 0.f, 0.f, 0.f};

#pragma unroll
    for (int kt = 0; kt < 8; ++kt) {
      int k0 = kt * 32 + q * 8;
      bf16x8 afrag[4];
#pragma unroll
      for (int mt = 0; mt < 4; ++mt)
        afrag[mt] = *(const bf16x8*)(WxT + (size_t)(nblk + mt * 16 + cl) * 256 + k0);
#pragma unroll
      for (int mt = 0; mt < 4; ++mt)
#pragma unroll
        for (int rt = 0; rt < 4; ++rt)
          acc[mt][rt] = __builtin_amdgcn_mfma_f32_16x16x32_bf16(
              afrag[mt], bfrag[kt][rt], acc[mt][rt], 0, 0, 0);
    }
#pragma unroll
    for (int mt = 0; mt < 4; ++mt) {
#pragma unroll
      for (int reg = 0; reg < 4; ++reg) {
        int n = nblk + mt * 16 + q * 4 + reg;
        float bb = bcat[n];
#pragma unroll
        for (int rt = 0; rt < 4; ++rt) {
          int rg16 = w * 4 + rt;  // = r>>4
          P[(((size_t)t * 16 + rg16) * 1024 + n) * 16 + cl] = f2bf(acc[mt][rt][reg] + bb);
        }
      }
    }
  }
}

// ---------- recurrent v13: v12 compute + heater blocks + P prefetch-ahead ----------
__global__ __launch_bounds__(512, 2) void lstm_recurrent(
    const unsigned short* __restrict__ WhT,
    const unsigned short* __restrict__ P,
    int* done, float* __restrict__ out) {
  // o-gate B-frags: [wave][block][kt][lane] bf16x8 = 128 KB (v5-proven layout)
  __shared__ bf16x8 o_w[8][2][8][64];
  // h double buffer, XOR-swizzled: byte ^= ((row&7)<<4).  16 KB.
  __shared__ unsigned short hbuf[2][16 * 256];
  __shared__ int heat_stop;

  int tid = threadIdx.x;
  int blk = blockIdx.x;

  if (blk >= 16) {
    // ---- HEATER: keep this CU busy (clock/DPM experiment).  One polling
    // wave (system atomic every ~500cy of dependent-rcp burn); other waves
    // spin on an LDS mailbox.  Exit when all 16 real WGs posted done.
    if (tid == 0) heat_stop = 0;
    __syncthreads();
    float a = 1.0f + (float)tid * 1e-6f;
    if (tid < 64) {
      while (__hip_atomic_load(done, __ATOMIC_RELAXED,
                               __HIP_MEMORY_SCOPE_SYSTEM) < 16) {
#pragma unroll
        for (int i = 0; i < 64; ++i) a = __builtin_amdgcn_rcpf(a + 1.0f);
        asm volatile("" ::"v"(a));
      }
      if (tid == 0) *(volatile int*)&heat_stop = 1;
    } else {
      while (*(volatile int*)&heat_stop == 0) {
#pragma unroll
        for (int i = 0; i < 32; ++i) a = __builtin_amdgcn_rcpf(a + 1.0f);
        asm volatile("" ::"v"(a));
      }
    }
    return;
  }

  int w = tid >> 6, lane = tid & 63, q = lane >> 4, cl = lane & 15;
  int x = blk;  // rows [16x, 16x+16)

  // ---- stage o-gate tiles into LDS: 8192 16B-chunks, 16 per thread
  for (int i = 0; i < 16; ++i) {
    int idx = tid + i * 512;
    int sw = idx >> 10, sb = (idx >> 9) & 1, skt = (idx >> 6) & 7, sl = idx & 63;
    int sq = sl >> 4, scl = sl & 15;
    int col = (2 * sw + sb) * 16 + scl;
    int k0 = skt * 32 + sq * 8;
    o_w[sw][sb][skt][sl] = *(const bf16x8*)(WhT + (size_t)(3 * 256 + col) * 256 + k0);
  }

  // ---- i,f,g gate tiles into VGPRs (static indexing only -- rule #20)
  bf16x8 wreg[2][3][8];  // [block][gate][kt]
#pragma unroll
  for (int b = 0; b < 2; ++b)
#pragma unroll
    for (int g = 0; g < 3; ++g)
#pragma unroll
      for (int kt = 0; kt < 8; ++kt) {
        int col = (2 * w + b) * 16 + cl;
        wreg[b][g][kt] =
            *(const bf16x8*)(WhT + (size_t)(g * 256 + col) * 256 + kt * 32 + q * 8);
      }

  // ---- zero h buffer 0 (h_0 = 0); swizzle irrelevant for zeros
  for (int i = tid; i < 2048; i += 512) ((unsigned int*)&hbuf[0][0])[i] = 0;
  __syncthreads();

  // A-read base (t-independent): row = cl, k-offset q*16 within kt-block,
  // swizzled.  Per kt: byte = abase ^ (kt*64) (bit-disjoint, verified v12).
  int abase = cl * 512 + ((q * 16) ^ ((cl & 7) << 4));

  float creg[2][4] = {{0.f, 0.f, 0.f, 0.f}, {0.f, 0.f, 0.f, 0.f}};

  // ---- P double buffer: pvc = step t (ready), pvn = prefetch for t+1.
  bf16x4 pvA[2][4], pvB[2][4];
#pragma unroll
  for (int b = 0; b < 2; ++b) {
    int colb = 32 * w + b * 16 + cl;
#pragma unroll
    for (int g = 0; g < 4; ++g)
      pvA[b][g] = *(const bf16x4*)(
          P + (((size_t)0 * 16 + x) * 1024 + g * 256 + colb) * 16 + q * 4);
  }

  auto body = [&](int t, bf16x4 (&pvc)[2][4], bf16x4 (&pvn)[2][4]) {
    int rb = t & 1;
    bool lastt = (t == STEPS - 1);
    const unsigned short* hr = &hbuf[rb][0];
    unsigned short* hw = &hbuf[rb ^ 1][0];

    // prefetch P for t+1 (issued now, consumed next step -> full-step lead)
    if (t + 1 < STEPS) {
#pragma unroll
      for (int b = 0; b < 2; ++b) {
        int colb = 32 * w + b * 16 + cl;
#pragma unroll
        for (int g = 0; g < 4; ++g)
          pvn[b][g] = *(const bf16x4*)(
              P + (((size_t)(t + 1) * 16 + x) * 1024 + g * 256 + colb) * 16 + q * 4);
      }
    }

#pragma unroll
    for (int b = 0; b < 2; ++b) {
      f32x4 acc[4];
#pragma unroll
      for (int g = 0; g < 4; ++g) acc[g] = f32x4{0.f, 0.f, 0.f, 0.f};

#pragma unroll
      for (int kt = 0; kt < 8; ++kt) {
        bf16x8 af = *(const bf16x8*)(hr + ((abase ^ (kt * 64)) >> 1));
        acc[0] = __builtin_amdgcn_mfma_f32_16x16x32_bf16(af, wreg[b][0][kt], acc[0], 0, 0, 0);
        acc[1] = __builtin_amdgcn_mfma_f32_16x16x32_bf16(af, wreg[b][1][kt], acc[1], 0, 0, 0);
        acc[2] = __builtin_amdgcn_mfma_f32_16x16x32_bf16(af, wreg[b][2][kt], acc[2], 0, 0, 0);
        acc[3] = __builtin_amdgcn_mfma_f32_16x16x32_bf16(af, o_w[w][b][kt][lane], acc[3], 0, 0, 0);
      }

      // EW: lane (q,cl) owns rows q*4+e, col 32w+b*16+cl; all 4 gates local.
      int colb = 32 * w + b * 16 + cl;
#pragma unroll
      for (int e = 0; e < 4; ++e) {
        float pi = acc[0][e] + bf2f((unsigned short)pvc[b][0][e]);
        float pf = acc[1][e] + bf2f((unsigned short)pvc[b][1][e]);
        float pg = acc[2][e] + bf2f((unsigned short)pvc[b][2][e]);
        float po = acc[3][e] + bf2f((unsigned short)pvc[b][3][e]);
        float ig = sig_f(pi), fg = sig_f(pf), gg = tanh_f(pg), og = sig_f(po);
        float cn = fg * creg[b][e] + ig * gg;
        creg[b][e] = cn;
        float hn = og * tanh_f(cn);
        int r = q * 4 + e;
        if (!lastt) {
          int wb = r * 512 + ((colb * 2) ^ ((r & 7) << 4));
          hw[wb >> 1] = f2bf(hn);
        } else {
          out[(size_t)(x * 16 + r) * 256 + colb] = hn;
          out[65536 + (size_t)(x * 16 + r) * 256 + colb] = cn;
        }
      }
    }

    __syncthreads();  // h(t+1) complete before step t+1 reads it
  };

  for (int t = 0; t < STEPS; t += 2) {
    body(t, pvA, pvB);
    if (t + 1 < STEPS) body(t + 1, pvB, pvA);
  }

  // signal heaters (after this WG's work; out-store visibility irrelevant here)
  if (tid == 0)
    __hip_atomic_fetch_add(done, 1, __ATOMIC_RELAXED, __HIP_MEMORY_SCOPE_SYSTEM);
}

extern "C" void kernel_launch(void* const* d_in, const int* in_sizes, int n_in,
                              void* d_out, int out_size, void* d_ws, size_t ws_size,
                              hipStream_t stream) {
  const float* x = (const float*)d_in[0];
  const float* wx0 = (const float*)d_in[1];
  const float* wx1 = (const float*)d_in[5];
  const float* wx2 = (const float*)d_in[9];
  const float* wx3 = (const float*)d_in[13];
  const float* wh0 = (const float*)d_in[3];
  const float* wh1 = (const float*)d_in[7];
  const float* wh2 = (const float*)d_in[11];
  const float* wh3 = (const float*)d_in[15];
  const float* bx0 = (const float*)d_in[2];
  const float* bx1 = (const float*)d_in[6];
  const float* bx2 = (const float*)d_in[10];
  const float* bx3 = (const float*)d_in[14];
  const float* bh0 = (const float*)d_in[4];
  const float* bh1 = (const float*)d_in[8];
  const float* bh2 = (const float*)d_in[12];
  const float* bh3 = (const float*)d_in[16];

  char* ws = (char*)d_ws;
  unsigned short* WxT = (unsigned short*)(ws + 0);          // dead after precompute
  unsigned short* WhT = (unsigned short*)(ws + 524288);
  float* bcat = (float*)(ws + 1048576);
  unsigned short* P = (unsigned short*)(ws + 1052672);      // [t][rg16][n][16] bf16
  int* done = (int*)ws;                                     // overlays dead WxT

  lstm_prep_w<<<dim3(8, 8, 8), 256, 0, stream>>>(wx0, wx1, wx2, wx3,
                                                 wh0, wh1, wh2, wh3, WxT, WhT);
  lstm_prep_b<<<4, 256, 0, stream>>>(bx0, bx1, bx2, bx3, bh0, bh1, bh2, bh3, bcat);
  lstm_precompute<<<dim3(255, 2), 256, 0, stream>>>(x, WxT, bcat, P);
  hipMemsetAsync(ws, 0, 256, stream);  // done=0 (after precompute's WxT reads)
  lstm_recurrent<<<dim3(256), 512, 0, stream>>>(WhT, P, done, (float*)d_out);
}

// Round 5
// 1373.739 us; speedup vs baseline: 1.2383x; 1.2383x over previous
//
#include <hip/hip_runtime.h>

// LSTM_77893526880768: B=T=F=H=256.  256 independent row-chains, 255 steps.
//
// v14 = v12 structure, 2x CUs via row-split + EW lane redistribution.
//
// Evidence ladder:
//   v9  (64 WG, cross-WG flags):   4.78us/step   v10 (wave flags): 5.14
//   v11 (2 chains/WG):             9.39us/step   v12 (intra-WG):   5.24
//   v13 (v12 + 240 heater CUs at 88% VALUBusy): 5.9us/step -> clock does
//   NOT respond to utilization.  But MFMA-cycle arithmetic on v9 AND v12
//   independently gives f ~= 730 MHz => clock is FIXED ~750 MHz here.
//   At 750 MHz v12's step is fully explained: MFMA 620cy/SIMD + EW ~1900
//   (8 cells/thread x ~38 VALU + 10 trans) + conflicts 130 + barrier 400.
//   v9 vs v12 invariance was coincidence: v9 = 1300 compute + 2200 sync,
//   v12 = 3150 compute + 700 sync.  EW dominates; rows are independent =>
//   split rows across 2x CUs (sync-free), redistribute EW across all lanes.
//
// v14: 32 WGs x 512 thr, WG x owns rows [8x,8x+8) x all 256 cols.
//   MFMA unchanged (A rows 8..15 zero; per-CU MFMA cycles invariant).
//   C-layout puts valid rows on q<2 lanes only => redistribute via
//   shfl_xor(acc[g][2..3], 32): lane (q,cl) owns rows rloc0={0,4,2,6}[q]
//   +{0,1}, 2 cells x 2 col-blocks = 4 cells/thread (was 8).
//   Weights CU-resident as v12: i,f,g in VGPR (static idx), o in LDS 128KB.
//   h in swizzled LDS dbuf (byte ^= (row&7)<<4, both sides).  One
//   __syncthreads per step.  P prefetched one step ahead (pvA/pvB).
//
// Workspace layout:
//   [0, 512K)       WxT bf16   (dead after precompute)
//   [512K, 1M)      WhT bf16
//   [1M, 1M+4K)     bcat fp32
//   [1M+4K, ...)    P bf16  [t][rg16][n][16] = 133,693,440 B

#define STEPS 255

typedef short bf16x8 __attribute__((ext_vector_type(8)));
typedef short bf16x4 __attribute__((ext_vector_type(4)));
typedef short bf16x2 __attribute__((ext_vector_type(2)));
typedef float f32x4  __attribute__((ext_vector_type(4)));

__device__ inline unsigned short f2bf(float f) {
  unsigned int u = __float_as_uint(f);
  unsigned int r = (u + 0x7FFFu + ((u >> 16) & 1u)) >> 16;  // RNE
  return (unsigned short)r;
}
__device__ inline float bf2f(unsigned short s) {
  return __uint_as_float(((unsigned int)s) << 16);
}
__device__ inline float sig_f(float x) {
  float e = exp2f(-1.442695041f * x);
  return __builtin_amdgcn_rcpf(1.0f + e);
}
__device__ inline float tanh_f(float x) {
  float e = exp2f(-2.885390082f * x);
  return 2.0f * __builtin_amdgcn_rcpf(1.0f + e) - 1.0f;
}

// ---------- prep: W transpose (W[k][j] fp32 -> WT[g*256+j][k] bf16) ----------
__global__ __launch_bounds__(256) void lstm_prep_w(
    const float* __restrict__ m0, const float* __restrict__ m1,
    const float* __restrict__ m2, const float* __restrict__ m3,
    const float* __restrict__ m4, const float* __restrict__ m5,
    const float* __restrict__ m6, const float* __restrict__ m7,
    unsigned short* __restrict__ WxT, unsigned short* __restrict__ WhT) {
  const float* mats[8] = {m0, m1, m2, m3, m4, m5, m6, m7};
  int mat = blockIdx.z;
  const float* W = mats[mat];
  unsigned short* out = (mat < 4 ? WxT : WhT) + (size_t)(mat & 3) * 256 * 256;
  int kblk = blockIdx.x * 32, jblk = blockIdx.y * 32;
  __shared__ float tile[32][33];
  int tx = threadIdx.x & 31, ty = threadIdx.x >> 5;
#pragma unroll
  for (int i = 0; i < 4; ++i) {
    int kk = ty + i * 8;
    tile[kk][tx] = W[(size_t)(kblk + kk) * 256 + jblk + tx];
  }
  __syncthreads();
#pragma unroll
  for (int i = 0; i < 4; ++i) {
    int jj = ty + i * 8;
    out[(size_t)(jblk + jj) * 256 + kblk + tx] = f2bf(tile[tx][jj]);
  }
}

// ---------- prep: bias fold ----------
__global__ void lstm_prep_b(
    const float* __restrict__ bx0, const float* __restrict__ bx1,
    const float* __restrict__ bx2, const float* __restrict__ bx3,
    const float* __restrict__ bh0, const float* __restrict__ bh1,
    const float* __restrict__ bh2, const float* __restrict__ bh3,
    float* __restrict__ bcat) {
  const float* bx[4] = {bx0, bx1, bx2, bx3};
  const float* bh[4] = {bh0, bh1, bh2, bh3};
  int i = blockIdx.x * 256 + threadIdx.x;
  int g = i >> 8, j = i & 255;
  bcat[i] = bx[g][j] + bh[g][j];
}

// ---------- precompute: P[t][rg16][n][rl] = bcat[n] + sum_k x[r,t,k] Wx[k,n] ----------
// grid (255, 2): blockIdx.y selects 8 of the 16 n-blocks (x-frags duplicated).
__global__ __launch_bounds__(256, 1) void lstm_precompute(
    const float* __restrict__ x, const unsigned short* __restrict__ WxT,
    const float* __restrict__ bcat, unsigned short* __restrict__ P) {
  int t = blockIdx.x;
  int tid = threadIdx.x;
  int w = tid >> 6, lane = tid & 63, q = lane >> 4, cl = lane & 15;
  int rbase = w * 64;

  bf16x8 bfrag[8][4];
#pragma unroll
  for (int kt = 0; kt < 8; ++kt) {
    int k0 = kt * 32 + q * 8;
#pragma unroll
    for (int rt = 0; rt < 4; ++rt) {
      const float* xp = x + (((size_t)(rbase + rt * 16 + cl) * 256 + t) * 256 + k0);
      f32x4 lo = *(const f32x4*)xp;
      f32x4 hi = *(const f32x4*)(xp + 4);
      bf16x8 bv;
      bv[0] = (short)f2bf(lo[0]); bv[1] = (short)f2bf(lo[1]);
      bv[2] = (short)f2bf(lo[2]); bv[3] = (short)f2bf(lo[3]);
      bv[4] = (short)f2bf(hi[0]); bv[5] = (short)f2bf(hi[1]);
      bv[6] = (short)f2bf(hi[2]); bv[7] = (short)f2bf(hi[3]);
      bfrag[kt][rt] = bv;
    }
  }

  for (int nbi = 0; nbi < 8; ++nbi) {
    int nblk = (blockIdx.y * 8 + nbi) * 64;
    f32x4 acc[4][4];
#pragma unroll
    for (int a = 0; a < 4; ++a)
#pragma unroll
      for (int b = 0; b < 4; ++b) acc[a][b] = f32x4{0.f, 0.f, 0.f, 0.f};

#pragma unroll
    for (int kt = 0; kt < 8; ++kt) {
      int k0 = kt * 32 + q * 8;
      bf16x8 afrag[4];
#pragma unroll
      for (int mt = 0; mt < 4; ++mt)
        afrag[mt] = *(const bf16x8*)(WxT + (size_t)(nblk + mt * 16 + cl) * 256 + k0);
#pragma unroll
      for (int mt = 0; mt < 4; ++mt)
#pragma unroll
        for (int rt = 0; rt < 4; ++rt)
          acc[mt][rt] = __builtin_amdgcn_mfma_f32_16x16x32_bf16(
              afrag[mt], bfrag[kt][rt], acc[mt][rt], 0, 0, 0);
    }
#pragma unroll
    for (int mt = 0; mt < 4; ++mt) {
#pragma unroll
      for (int reg = 0; reg < 4; ++reg) {
        int n = nblk + mt * 16 + q * 4 + reg;
        float bb = bcat[n];
#pragma unroll
        for (int rt = 0; rt < 4; ++rt) {
          int rg16 = w * 4 + rt;  // = r>>4
          P[(((size_t)t * 16 + rg16) * 1024 + n) * 16 + cl] = f2bf(acc[mt][rt][reg] + bb);
        }
      }
    }
  }
}

// ---------- recurrent v14: 32 WGs x 8 rows, EW redistributed across lanes ----------
__global__ __launch_bounds__(512, 2) void lstm_recurrent(
    const unsigned short* __restrict__ WhT,
    const unsigned short* __restrict__ P,
    float* __restrict__ out) {
  // o-gate B-frags: [wave][block][kt][lane] bf16x8 = 128 KB (v5-proven layout)
  __shared__ bf16x8 o_w[8][2][8][64];
  // h double buffer, XOR-swizzled: byte ^= ((row&7)<<4).  16 KB.
  // Rows 0..7 live; rows 8..15 stay zero forever (A-tile zero-padding).
  __shared__ unsigned short hbuf[2][16 * 256];

  int tid = threadIdx.x;
  int w = tid >> 6, lane = tid & 63, q = lane >> 4, cl = lane & 15;
  int x = blockIdx.x;           // rows [8x, 8x+8)
  int rg16 = x >> 1;            // P row-group
  int idxb = (x & 1) * 8;       // P idx15 base for this WG's rows

  // ---- stage o-gate tiles into LDS: 8192 16B-chunks, 16 per thread
  for (int i = 0; i < 16; ++i) {
    int idx = tid + i * 512;
    int sw = idx >> 10, sb = (idx >> 9) & 1, skt = (idx >> 6) & 7, sl = idx & 63;
    int sq = sl >> 4, scl = sl & 15;
    int col = (2 * sw + sb) * 16 + scl;
    int k0 = skt * 32 + sq * 8;
    o_w[sw][sb][skt][sl] = *(const bf16x8*)(WhT + (size_t)(3 * 256 + col) * 256 + k0);
  }

  // ---- i,f,g gate tiles into VGPRs (static indexing only -- rule #20)
  bf16x8 wreg[2][3][8];  // [block][gate][kt]
#pragma unroll
  for (int b = 0; b < 2; ++b)
#pragma unroll
    for (int g = 0; g < 3; ++g)
#pragma unroll
      for (int kt = 0; kt < 8; ++kt) {
        int col = (2 * w + b) * 16 + cl;
        wreg[b][g][kt] =
            *(const bf16x8*)(WhT + (size_t)(g * 256 + col) * 256 + kt * 32 + q * 8);
      }

  // ---- zero BOTH h buffers (rows 8..15 never written; h_0 = 0)
  for (int i = tid; i < 4096; i += 512) ((unsigned int*)&hbuf[0][0])[i] = 0;
  __syncthreads();

  // A-read base (t-independent): row = cl, k-offset q*16 within kt-block,
  // swizzled.  Per kt: byte = abase ^ (kt*64) (bit-disjoint, v12-proven).
  int abase = cl * 512 + ((q * 16) ^ ((cl & 7) << 4));

  // EW ownership after redistribution: lane (q,cl) owns local rows
  // rloc0={0,4,2,6}[q] + {0,1}, cols 32w + b*16 + cl.
  int rloc0 = (q & 1) * 4 + (q >> 1) * 2;
  bool qlo = (q < 2);

  float creg[2][2] = {{0.f, 0.f}, {0.f, 0.f}};  // [block][cell]

  // ---- P double buffer: pvc = step t (ready), pvn = prefetch for t+1.
  bf16x2 pvA[2][4], pvB[2][4];
#pragma unroll
  for (int b = 0; b < 2; ++b) {
    int colb = 32 * w + b * 16 + cl;
#pragma unroll
    for (int g = 0; g < 4; ++g)
      pvA[b][g] = *(const bf16x2*)(
          P + (((size_t)0 * 16 + rg16) * 1024 + g * 256 + colb) * 16 + idxb + rloc0);
  }

  auto body = [&](int t, bf16x2 (&pvc)[2][4], bf16x2 (&pvn)[2][4]) {
    int rb = t & 1;
    bool lastt = (t == STEPS - 1);
    const unsigned short* hr = &hbuf[rb][0];
    unsigned short* hw = &hbuf[rb ^ 1][0];

    // prefetch P for t+1 (issued now, consumed next step -> full-step lead)
    if (t + 1 < STEPS) {
#pragma unroll
      for (int b = 0; b < 2; ++b) {
        int colb = 32 * w + b * 16 + cl;
#pragma unroll
        for (int g = 0; g < 4; ++g)
          pvn[b][g] = *(const bf16x2*)(
              P + (((size_t)(t + 1) * 16 + rg16) * 1024 + g * 256 + colb) * 16 + idxb + rloc0);
      }
    }

#pragma unroll
    for (int b = 0; b < 2; ++b) {
      f32x4 acc[4];
#pragma unroll
      for (int g = 0; g < 4; ++g) acc[g] = f32x4{0.f, 0.f, 0.f, 0.f};

#pragma unroll
      for (int kt = 0; kt < 8; ++kt) {
        bf16x8 af = *(const bf16x8*)(hr + ((abase ^ (kt * 64)) >> 1));
        acc[0] = __builtin_amdgcn_mfma_f32_16x16x32_bf16(af, wreg[b][0][kt], acc[0], 0, 0, 0);
        acc[1] = __builtin_amdgcn_mfma_f32_16x16x32_bf16(af, wreg[b][1][kt], acc[1], 0, 0, 0);
        acc[2] = __builtin_amdgcn_mfma_f32_16x16x32_bf16(af, wreg[b][2][kt], acc[2], 0, 0, 0);
        acc[3] = __builtin_amdgcn_mfma_f32_16x16x32_bf16(af, o_w[w][b][kt][lane], acc[3], 0, 0, 0);
      }

      // ---- redistribute C rows {2,3,6,7} (held by q<2 at e=2,3) to q>=2
      float sh2[4], sh3[4];
#pragma unroll
      for (int g = 0; g < 4; ++g) {
        sh2[g] = __shfl_xor(acc[g][2], 32, 64);
        sh3[g] = __shfl_xor(acc[g][3], 32, 64);
      }

      // ---- EW: 2 cells per lane per block; all 4 gates lane-local.
      int colb = 32 * w + b * 16 + cl;
#pragma unroll
      for (int c = 0; c < 2; ++c) {
        float a0 = qlo ? acc[0][c] : (c ? sh3[0] : sh2[0]);
        float a1 = qlo ? acc[1][c] : (c ? sh3[1] : sh2[1]);
        float a2 = qlo ? acc[2][c] : (c ? sh3[2] : sh2[2]);
        float a3 = qlo ? acc[3][c] : (c ? sh3[3] : sh2[3]);
        float pi = a0 + bf2f((unsigned short)pvc[b][0][c]);
        float pf = a1 + bf2f((unsigned short)pvc[b][1][c]);
        float pg = a2 + bf2f((unsigned short)pvc[b][2][c]);
        float po = a3 + bf2f((unsigned short)pvc[b][3][c]);
        float ig = sig_f(pi), fg = sig_f(pf), gg = tanh_f(pg), og = sig_f(po);
        float cn = fg * creg[b][c] + ig * gg;
        creg[b][c] = cn;
        float hn = og * tanh_f(cn);
        int r = rloc0 + c;  // local row, 0..7
        if (!lastt) {
          int wb = r * 512 + ((colb * 2) ^ ((r & 7) << 4));
          hw[wb >> 1] = f2bf(hn);
        } else {
          out[(size_t)(x * 8 + r) * 256 + colb] = hn;
          out[65536 + (size_t)(x * 8 + r) * 256 + colb] = cn;
        }
      }
    }

    __syncthreads();  // h(t+1) complete before step t+1 reads it
  };

  for (int t = 0; t < STEPS; t += 2) {
    body(t, pvA, pvB);
    if (t + 1 < STEPS) body(t + 1, pvB, pvA);
  }
}

extern "C" void kernel_launch(void* const* d_in, const int* in_sizes, int n_in,
                              void* d_out, int out_size, void* d_ws, size_t ws_size,
                              hipStream_t stream) {
  const float* x = (const float*)d_in[0];
  const float* wx0 = (const float*)d_in[1];
  const float* wx1 = (const float*)d_in[5];
  const float* wx2 = (const float*)d_in[9];
  const float* wx3 = (const float*)d_in[13];
  const float* wh0 = (const float*)d_in[3];
  const float* wh1 = (const float*)d_in[7];
  const float* wh2 = (const float*)d_in[11];
  const float* wh3 = (const float*)d_in[15];
  const float* bx0 = (const float*)d_in[2];
  const float* bx1 = (const float*)d_in[6];
  const float* bx2 = (const float*)d_in[10];
  const float* bx3 = (const float*)d_in[14];
  const float* bh0 = (const float*)d_in[4];
  const float* bh1 = (const float*)d_in[8];
  const float* bh2 = (const float*)d_in[12];
  const float* bh3 = (const float*)d_in[16];

  char* ws = (char*)d_ws;
  unsigned short* WxT = (unsigned short*)(ws + 0);          // dead after precompute
  unsigned short* WhT = (unsigned short*)(ws + 524288);
  float* bcat = (float*)(ws + 1048576);
  unsigned short* P = (unsigned short*)(ws + 1052672);      // [t][rg16][n][16] bf16

  lstm_prep_w<<<dim3(8, 8, 8), 256, 0, stream>>>(wx0, wx1, wx2, wx3,
                                                 wh0, wh1, wh2, wh3, WxT, WhT);
  lstm_prep_b<<<4, 256, 0, stream>>>(bx0, bx1, bx2, bx3, bh0, bh1, bh2, bh3, bcat);
  lstm_precompute<<<dim3(255, 2), 256, 0, stream>>>(x, WxT, bcat, P);
  lstm_recurrent<<<dim3(32), 512, 0, stream>>>(WhT, P, (float*)d_out);
}

// Round 6
// 975.157 us; speedup vs baseline: 1.7444x; 1.4087x over previous
//
#include <hip/hip_runtime.h>

// LSTM_77893526880768: B=T=F=H=256.  256 independent row-chains, 255 steps.
//
// v15 = v14 structure + weights ACTUALLY register-resident.
//
// Evidence ladder:
//   v9 4.78us/step | v10 5.14 | v11 9.39 | v12 5.24 | v13 5.9 (heaters:
//   clock does NOT respond to load) | v14 4.42 (32 WG x 8 rows).
//   Clock: MFMA-cycle arithmetic on v9, v12, v14 independently gives
//   f ~= 730-750 MHz FIXED => v14 step = ~3300 cy.
//   KEY v14 finding: VGPR_Count=128 but wreg[2][3][8] needs 192 VGPRs =>
//   compiler rematerialized the weight loads: 48 global_load_dwordx4 per
//   thread per step from L2-resident WhT (legal: const+restrict, no fence).
//   Issue budget/SIMD/step: MFMA 620 + VALU ~930 (28% on-active) + LDS
//   ~500 (o_w 16x b128 + h) + VMEM remat ~400 + barrier/stalls ~850 = 3300.
//
// v15 removes the remat term:
//   - working set shrunk: single pv buffer (loads at step start are still
//     covered by the ~800cy MFMA phase; L2/HBM latency ~300cy @750MHz),
//     redistribution sh[] sequenced (4 live, not 8), no 2-step unroll.
//     192 weights + ~60 working <= 256 cap (launch_bounds(512,2)).
//   - asm volatile("":::"memory") after the weight loads: rematerializing
//     a global load across a memory clobber is illegal => values must stay
//     in VGPRs.  Observable: VGPR_Count ~128 -> ~250.
//
// v14-proven and kept: 32 WGs x 8 rows x all 256 cols; i,f,g weights per
// wave (2 col-blocks), o-gate in 128KB LDS (v5 layout); h in 16KB swizzled
// LDS dbuf (byte ^= (row&7)<<4, both sides); EW redistribution via
// shfl_xor(32) so all lanes own 2 cells x 2 blocks; one __syncthreads/step.
//
// Workspace layout:
//   [0, 512K)       WxT bf16   (dead after precompute)
//   [512K, 1M)      WhT bf16
//   [1M, 1M+4K)     bcat fp32
//   [1M+4K, ...)    P bf16  [t][rg16][n][16] = 133,693,440 B

#define STEPS 255

typedef short bf16x8 __attribute__((ext_vector_type(8)));
typedef short bf16x4 __attribute__((ext_vector_type(4)));
typedef short bf16x2 __attribute__((ext_vector_type(2)));
typedef float f32x4  __attribute__((ext_vector_type(4)));

__device__ inline unsigned short f2bf(float f) {
  unsigned int u = __float_as_uint(f);
  unsigned int r = (u + 0x7FFFu + ((u >> 16) & 1u)) >> 16;  // RNE
  return (unsigned short)r;
}
__device__ inline float bf2f(unsigned short s) {
  return __uint_as_float(((unsigned int)s) << 16);
}
__device__ inline float sig_f(float x) {
  float e = exp2f(-1.442695041f * x);
  return __builtin_amdgcn_rcpf(1.0f + e);
}
__device__ inline float tanh_f(float x) {
  float e = exp2f(-2.885390082f * x);
  return 2.0f * __builtin_amdgcn_rcpf(1.0f + e) - 1.0f;
}

// ---------- prep: W transpose (W[k][j] fp32 -> WT[g*256+j][k] bf16) ----------
__global__ __launch_bounds__(256) void lstm_prep_w(
    const float* __restrict__ m0, const float* __restrict__ m1,
    const float* __restrict__ m2, const float* __restrict__ m3,
    const float* __restrict__ m4, const float* __restrict__ m5,
    const float* __restrict__ m6, const float* __restrict__ m7,
    unsigned short* __restrict__ WxT, unsigned short* __restrict__ WhT) {
  const float* mats[8] = {m0, m1, m2, m3, m4, m5, m6, m7};
  int mat = blockIdx.z;
  const float* W = mats[mat];
  unsigned short* out = (mat < 4 ? WxT : WhT) + (size_t)(mat & 3) * 256 * 256;
  int kblk = blockIdx.x * 32, jblk = blockIdx.y * 32;
  __shared__ float tile[32][33];
  int tx = threadIdx.x & 31, ty = threadIdx.x >> 5;
#pragma unroll
  for (int i = 0; i < 4; ++i) {
    int kk = ty + i * 8;
    tile[kk][tx] = W[(size_t)(kblk + kk) * 256 + jblk + tx];
  }
  __syncthreads();
#pragma unroll
  for (int i = 0; i < 4; ++i) {
    int jj = ty + i * 8;
    out[(size_t)(jblk + jj) * 256 + kblk + tx] = f2bf(tile[tx][jj]);
  }
}

// ---------- prep: bias fold ----------
__global__ void lstm_prep_b(
    const float* __restrict__ bx0, const float* __restrict__ bx1,
    const float* __restrict__ bx2, const float* __restrict__ bx3,
    const float* __restrict__ bh0, const float* __restrict__ bh1,
    const float* __restrict__ bh2, const float* __restrict__ bh3,
    float* __restrict__ bcat) {
  const float* bx[4] = {bx0, bx1, bx2, bx3};
  const float* bh[4] = {bh0, bh1, bh2, bh3};
  int i = blockIdx.x * 256 + threadIdx.x;
  int g = i >> 8, j = i & 255;
  bcat[i] = bx[g][j] + bh[g][j];
}

// ---------- precompute: P[t][rg16][n][rl] = bcat[n] + sum_k x[r,t,k] Wx[k,n] ----------
// grid (255, 2): blockIdx.y selects 8 of the 16 n-blocks (x-frags duplicated).
__global__ __launch_bounds__(256, 1) void lstm_precompute(
    const float* __restrict__ x, const unsigned short* __restrict__ WxT,
    const float* __restrict__ bcat, unsigned short* __restrict__ P) {
  int t = blockIdx.x;
  int tid = threadIdx.x;
  int w = tid >> 6, lane = tid & 63, q = lane >> 4, cl = lane & 15;
  int rbase = w * 64;

  bf16x8 bfrag[8][4];
#pragma unroll
  for (int kt = 0; kt < 8; ++kt) {
    int k0 = kt * 32 + q * 8;
#pragma unroll
    for (int rt = 0; rt < 4; ++rt) {
      const float* xp = x + (((size_t)(rbase + rt * 16 + cl) * 256 + t) * 256 + k0);
      f32x4 lo = *(const f32x4*)xp;
      f32x4 hi = *(const f32x4*)(xp + 4);
      bf16x8 bv;
      bv[0] = (short)f2bf(lo[0]); bv[1] = (short)f2bf(lo[1]);
      bv[2] = (short)f2bf(lo[2]); bv[3] = (short)f2bf(lo[3]);
      bv[4] = (short)f2bf(hi[0]); bv[5] = (short)f2bf(hi[1]);
      bv[6] = (short)f2bf(hi[2]); bv[7] = (short)f2bf(hi[3]);
      bfrag[kt][rt] = bv;
    }
  }

  for (int nbi = 0; nbi < 8; ++nbi) {
    int nblk = (blockIdx.y * 8 + nbi) * 64;
    f32x4 acc[4][4];
#pragma unroll
    for (int a = 0; a < 4; ++a)
#pragma unroll
      for (int b = 0; b < 4; ++b) acc[a][b] = f32x4{0.f, 0.f, 0.f, 0.f};

#pragma unroll
    for (int kt = 0; kt < 8; ++kt) {
      int k0 = kt * 32 + q * 8;
      bf16x8 afrag[4];
#pragma unroll
      for (int mt = 0; mt < 4; ++mt)
        afrag[mt] = *(const bf16x8*)(WxT + (size_t)(nblk + mt * 16 + cl) * 256 + k0);
#pragma unroll
      for (int mt = 0; mt < 4; ++mt)
#pragma unroll
        for (int rt = 0; rt < 4; ++rt)
          acc[mt][rt] = __builtin_amdgcn_mfma_f32_16x16x32_bf16(
              afrag[mt], bfrag[kt][rt], acc[mt][rt], 0, 0, 0);
    }
#pragma unroll
    for (int mt = 0; mt < 4; ++mt) {
#pragma unroll
      for (int reg = 0; reg < 4; ++reg) {
        int n = nblk + mt * 16 + q * 4 + reg;
        float bb = bcat[n];
#pragma unroll
        for (int rt = 0; rt < 4; ++rt) {
          int rg16 = w * 4 + rt;  // = r>>4
          P[(((size_t)t * 16 + rg16) * 1024 + n) * 16 + cl] = f2bf(acc[mt][rt][reg] + bb);
        }
      }
    }
  }
}

// ---------- recurrent v15: 32 WGs x 8 rows, weights pinned in VGPRs ----------
__global__ __launch_bounds__(512, 2) void lstm_recurrent(
    const unsigned short* __restrict__ WhT,
    const unsigned short* __restrict__ P,
    float* __restrict__ out) {
  // o-gate B-frags: [wave][block][kt][lane] bf16x8 = 128 KB (v5-proven layout)
  __shared__ bf16x8 o_w[8][2][8][64];
  // h double buffer, XOR-swizzled: byte ^= ((row&7)<<4).  16 KB.
  // Rows 0..7 live; rows 8..15 stay zero forever (A-tile zero-padding).
  __shared__ unsigned short hbuf[2][16 * 256];

  int tid = threadIdx.x;
  int w = tid >> 6, lane = tid & 63, q = lane >> 4, cl = lane & 15;
  int x = blockIdx.x;           // rows [8x, 8x+8)
  int rg16 = x >> 1;            // P row-group
  int idxb = (x & 1) * 8;       // P idx15 base for this WG's rows

  // ---- stage o-gate tiles into LDS: 8192 16B-chunks, 16 per thread
  for (int i = 0; i < 16; ++i) {
    int idx = tid + i * 512;
    int sw = idx >> 10, sb = (idx >> 9) & 1, skt = (idx >> 6) & 7, sl = idx & 63;
    int sq = sl >> 4, scl = sl & 15;
    int col = (2 * sw + sb) * 16 + scl;
    int k0 = skt * 32 + sq * 8;
    o_w[sw][sb][skt][sl] = *(const bf16x8*)(WhT + (size_t)(3 * 256 + col) * 256 + k0);
  }

  // ---- i,f,g gate tiles into VGPRs (static indexing only -- rule #20)
  bf16x8 wreg[2][3][8];  // [block][gate][kt] = 48 frags = 192 VGPRs
#pragma unroll
  for (int b = 0; b < 2; ++b)
#pragma unroll
    for (int g = 0; g < 3; ++g)
#pragma unroll
      for (int kt = 0; kt < 8; ++kt) {
        int col = (2 * w + b) * 16 + cl;
        wreg[b][g][kt] =
            *(const bf16x8*)(WhT + (size_t)(g * 256 + col) * 256 + kt * 32 + q * 8);
      }

  // ---- zero BOTH h buffers (rows 8..15 never written; h_0 = 0)
  for (int i = tid; i < 4096; i += 512) ((unsigned int*)&hbuf[0][0])[i] = 0;

  // Memory clobber: rematerializing the wreg global loads across this fence
  // is illegal => the 192 weight VGPRs must stay resident (v14's remat had
  // 48 in-loop global loads per thread per step; VGPR_Count 128 proved it).
  asm volatile("" ::: "memory");
  __syncthreads();

  // A-read base (t-independent): row = cl, k-offset q*16 within kt-block,
  // swizzled.  Per kt: byte = abase ^ (kt*64) (bit-disjoint, v12-proven).
  int abase = cl * 512 + ((q * 16) ^ ((cl & 7) << 4));

  // EW ownership after redistribution: lane (q,cl) owns local rows
  // rloc0={0,4,2,6}[q] + {0,1}, cols 32w + b*16 + cl.
  int rloc0 = (q & 1) * 4 + (q >> 1) * 2;
  bool qlo = (q < 2);

  float creg[2][2] = {{0.f, 0.f}, {0.f, 0.f}};  // [block][cell]

  for (int t = 0; t < STEPS; ++t) {
    int rb = t & 1;
    bool lastt = (t == STEPS - 1);
    const unsigned short* hr = &hbuf[rb][0];
    unsigned short* hw = &hbuf[rb ^ 1][0];

    // P loads for step t: issued at step start, consumed after the MFMA
    // phase (~800cy later) -> L2/HBM latency (~300cy) stays hidden.
    bf16x2 pv[2][4];
#pragma unroll
    for (int b = 0; b < 2; ++b) {
      int colb = 32 * w + b * 16 + cl;
#pragma unroll
      for (int g = 0; g < 4; ++g)
        pv[b][g] = *(const bf16x2*)(
            P + (((size_t)t * 16 + rg16) * 1024 + g * 256 + colb) * 16 + idxb + rloc0);
    }

#pragma unroll
    for (int b = 0; b < 2; ++b) {
      f32x4 acc[4];
#pragma unroll
      for (int g = 0; g < 4; ++g) acc[g] = f32x4{0.f, 0.f, 0.f, 0.f};

#pragma unroll
      for (int kt = 0; kt < 8; ++kt) {
        bf16x8 af = *(const bf16x8*)(hr + ((abase ^ (kt * 64)) >> 1));
        acc[0] = __builtin_amdgcn_mfma_f32_16x16x32_bf16(af, wreg[b][0][kt], acc[0], 0, 0, 0);
        acc[1] = __builtin_amdgcn_mfma_f32_16x16x32_bf16(af, wreg[b][1][kt], acc[1], 0, 0, 0);
        acc[2] = __builtin_amdgcn_mfma_f32_16x16x32_bf16(af, wreg[b][2][kt], acc[2], 0, 0, 0);
        acc[3] = __builtin_amdgcn_mfma_f32_16x16x32_bf16(af, o_w[w][b][kt][lane], acc[3], 0, 0, 0);
      }

      int colb = 32 * w + b * 16 + cl;
      // ---- cell 0: rows rloc0; C rows {2,3,6,7} come from q<2 via shfl.
      {
        float sh[4];
#pragma unroll
        for (int g = 0; g < 4; ++g) sh[g] = __shfl_xor(acc[g][2], 32, 64);
        float a0 = qlo ? acc[0][0] : sh[0];
        float a1 = qlo ? acc[1][0] : sh[1];
        float a2 = qlo ? acc[2][0] : sh[2];
        float a3 = qlo ? acc[3][0] : sh[3];
        float pi = a0 + bf2f((unsigned short)pv[b][0][0]);
        float pf = a1 + bf2f((unsigned short)pv[b][1][0]);
        float pg = a2 + bf2f((unsigned short)pv[b][2][0]);
        float po = a3 + bf2f((unsigned short)pv[b][3][0]);
        float ig = sig_f(pi), fg = sig_f(pf), gg = tanh_f(pg), og = sig_f(po);
        float cn = fg * creg[b][0] + ig * gg;
        creg[b][0] = cn;
        float hn = og * tanh_f(cn);
        int r = rloc0;
        if (!lastt) {
          int wb = r * 512 + ((colb * 2) ^ ((r & 7) << 4));
          hw[wb >> 1] = f2bf(hn);
        } else {
          out[(size_t)(x * 8 + r) * 256 + colb] = hn;
          out[65536 + (size_t)(x * 8 + r) * 256 + colb] = cn;
        }
      }
      // ---- cell 1: rows rloc0+1.
      {
        float sh[4];
#pragma unroll
        for (int g = 0; g < 4; ++g) sh[g] = __shfl_xor(acc[g][3], 32, 64);
        float a0 = qlo ? acc[0][1] : sh[0];
        float a1 = qlo ? acc[1][1] : sh[1];
        float a2 = qlo ? acc[2][1] : sh[2];
        float a3 = qlo ? acc[3][1] : sh[3];
        float pi = a0 + bf2f((unsigned short)pv[b][0][1]);
        float pf = a1 + bf2f((unsigned short)pv[b][1][1]);
        float pg = a2 + bf2f((unsigned short)pv[b][2][1]);
        float po = a3 + bf2f((unsigned short)pv[b][3][1]);
        float ig = sig_f(pi), fg = sig_f(pf), gg = tanh_f(pg), og = sig_f(po);
        float cn = fg * creg[b][1] + ig * gg;
        creg[b][1] = cn;
        float hn = og * tanh_f(cn);
        int r = rloc0 + 1;
        if (!lastt) {
          int wb = r * 512 + ((colb * 2) ^ ((r & 7) << 4));
          hw[wb >> 1] = f2bf(hn);
        } else {
          out[(size_t)(x * 8 + r) * 256 + colb] = hn;
          out[65536 + (size_t)(x * 8 + r) * 256 + colb] = cn;
        }
      }
    }

    __syncthreads();  // h(t+1) complete before step t+1 reads it
  }
}

extern "C" void kernel_launch(void* const* d_in, const int* in_sizes, int n_in,
                              void* d_out, int out_size, void* d_ws, size_t ws_size,
                              hipStream_t stream) {
  const float* x = (const float*)d_in[0];
  const float* wx0 = (const float*)d_in[1];
  const float* wx1 = (const float*)d_in[5];
  const float* wx2 = (const float*)d_in[9];
  const float* wx3 = (const float*)d_in[13];
  const float* wh0 = (const float*)d_in[3];
  const float* wh1 = (const float*)d_in[7];
  const float* wh2 = (const float*)d_in[11];
  const float* wh3 = (const float*)d_in[15];
  const float* bx0 = (const float*)d_in[2];
  const float* bx1 = (const float*)d_in[6];
  const float* bx2 = (const float*)d_in[10];
  const float* bx3 = (const float*)d_in[14];
  const float* bh0 = (const float*)d_in[4];
  const float* bh1 = (const float*)d_in[8];
  const float* bh2 = (const float*)d_in[12];
  const float* bh3 = (const float*)d_in[16];

  char* ws = (char*)d_ws;
  unsigned short* WxT = (unsigned short*)(ws + 0);          // dead after precompute
  unsigned short* WhT = (unsigned short*)(ws + 524288);
  float* bcat = (float*)(ws + 1048576);
  unsigned short* P = (unsigned short*)(ws + 1052672);      // [t][rg16][n][16] bf16

  lstm_prep_w<<<dim3(8, 8, 8), 256, 0, stream>>>(wx0, wx1, wx2, wx3,
                                                 wh0, wh1, wh2, wh3, WxT, WhT);
  lstm_prep_b<<<4, 256, 0, stream>>>(bx0, bx1, bx2, bx3, bh0, bh1, bh2, bh3, bcat);
  lstm_precompute<<<dim3(255, 2), 256, 0, stream>>>(x, WxT, bcat, P);
  lstm_recurrent<<<dim3(32), 512, 0, stream>>>(WhT, P, (float*)d_out);
}

// Round 7
// 830.161 us; speedup vs baseline: 2.0491x; 1.1747x over previous
//
#include <hip/hip_runtime.h>

// LSTM_77893526880768: B=T=F=H=256.  256 independent row-chains, 255 steps.
//
// v16 = v15 + row-split to 128 WGs x 2 rows (EW VALU is the scaling term).
//
// Evidence ladder:
//   v9 4.78us/step | v12 5.24 | v14 4.42 (32WGx8rows, remat found) |
//   v15 2.85 (weights pinned via asm memory clobber; VGPR_Count stayed 128
//   => pin likely landed in unified-file AGPR side, win is real).
//   Clock: MFMA-cycle arithmetic on v9/v12/v14/v15 all give ~730-750 MHz
//   FIXED (v13 heaters: clock does NOT respond to load).
//   v15 step budget (2135cy/SIMD): MFMA 620 (invariant to row-split) +
//   VALU ~940 (44% on-active; 10 trans ops x 8cy x 4 cells/thread) +
//   LDS ~300 + barrier ~275.  EW scales 1/WGs; CUs are free; => split.
//
// v16: 128 WGs x 512 thr, WG x owns rows [2x,2x+2) x all 256 cols.
//   Cells/thread: 4 -> 1.  Valid C rows {0,1} sit at q=0,e={0,1}; lane
//   (q,cl) owns cell (b=q>>1, r=q&1, col=32w+b*16+cl) via 3 shfl_xor per
//   gate (masks 16/32/48) + select.  h A-frag hoisted out of the block
//   loop (8 ds_read_b128/step, was 16).  Single pv cell (4 scalar loads).
//   Weights: i,f,g VGPR-pinned (asm clobber, v15-proven), o in 128KB LDS;
//   h in 16KB swizzled LDS dbuf (byte ^= (row&7)<<4); one barrier/step.
//
// Workspace layout:
//   [0, 512K)       WxT bf16   (dead after precompute)
//   [512K, 1M)      WhT bf16
//   [1M, 1M+4K)     bcat fp32
//   [1M+4K, ...)    P bf16  [t][rg16][n][16] = 133,693,440 B

#define STEPS 255

typedef short bf16x8 __attribute__((ext_vector_type(8)));
typedef short bf16x4 __attribute__((ext_vector_type(4)));
typedef float f32x4  __attribute__((ext_vector_type(4)));

__device__ inline unsigned short f2bf(float f) {
  unsigned int u = __float_as_uint(f);
  unsigned int r = (u + 0x7FFFu + ((u >> 16) & 1u)) >> 16;  // RNE
  return (unsigned short)r;
}
__device__ inline float bf2f(unsigned short s) {
  return __uint_as_float(((unsigned int)s) << 16);
}
__device__ inline float sig_f(float x) {
  float e = exp2f(-1.442695041f * x);
  return __builtin_amdgcn_rcpf(1.0f + e);
}
__device__ inline float tanh_f(float x) {
  float e = exp2f(-2.885390082f * x);
  return 2.0f * __builtin_amdgcn_rcpf(1.0f + e) - 1.0f;
}

// ---------- prep: W transpose (W[k][j] fp32 -> WT[g*256+j][k] bf16) ----------
__global__ __launch_bounds__(256) void lstm_prep_w(
    const float* __restrict__ m0, const float* __restrict__ m1,
    const float* __restrict__ m2, const float* __restrict__ m3,
    const float* __restrict__ m4, const float* __restrict__ m5,
    const float* __restrict__ m6, const float* __restrict__ m7,
    unsigned short* __restrict__ WxT, unsigned short* __restrict__ WhT) {
  const float* mats[8] = {m0, m1, m2, m3, m4, m5, m6, m7};
  int mat = blockIdx.z;
  const float* W = mats[mat];
  unsigned short* out = (mat < 4 ? WxT : WhT) + (size_t)(mat & 3) * 256 * 256;
  int kblk = blockIdx.x * 32, jblk = blockIdx.y * 32;
  __shared__ float tile[32][33];
  int tx = threadIdx.x & 31, ty = threadIdx.x >> 5;
#pragma unroll
  for (int i = 0; i < 4; ++i) {
    int kk = ty + i * 8;
    tile[kk][tx] = W[(size_t)(kblk + kk) * 256 + jblk + tx];
  }
  __syncthreads();
#pragma unroll
  for (int i = 0; i < 4; ++i) {
    int jj = ty + i * 8;
    out[(size_t)(jblk + jj) * 256 + kblk + tx] = f2bf(tile[tx][jj]);
  }
}

// ---------- prep: bias fold ----------
__global__ void lstm_prep_b(
    const float* __restrict__ bx0, const float* __restrict__ bx1,
    const float* __restrict__ bx2, const float* __restrict__ bx3,
    const float* __restrict__ bh0, const float* __restrict__ bh1,
    const float* __restrict__ bh2, const float* __restrict__ bh3,
    float* __restrict__ bcat) {
  const float* bx[4] = {bx0, bx1, bx2, bx3};
  const float* bh[4] = {bh0, bh1, bh2, bh3};
  int i = blockIdx.x * 256 + threadIdx.x;
  int g = i >> 8, j = i & 255;
  bcat[i] = bx[g][j] + bh[g][j];
}

// ---------- precompute: P[t][rg16][n][rl] = bcat[n] + sum_k x[r,t,k] Wx[k,n] ----------
// grid (255, 2): blockIdx.y selects 8 of the 16 n-blocks (x-frags duplicated).
__global__ __launch_bounds__(256, 1) void lstm_precompute(
    const float* __restrict__ x, const unsigned short* __restrict__ WxT,
    const float* __restrict__ bcat, unsigned short* __restrict__ P) {
  int t = blockIdx.x;
  int tid = threadIdx.x;
  int w = tid >> 6, lane = tid & 63, q = lane >> 4, cl = lane & 15;
  int rbase = w * 64;

  bf16x8 bfrag[8][4];
#pragma unroll
  for (int kt = 0; kt < 8; ++kt) {
    int k0 = kt * 32 + q * 8;
#pragma unroll
    for (int rt = 0; rt < 4; ++rt) {
      const float* xp = x + (((size_t)(rbase + rt * 16 + cl) * 256 + t) * 256 + k0);
      f32x4 lo = *(const f32x4*)xp;
      f32x4 hi = *(const f32x4*)(xp + 4);
      bf16x8 bv;
      bv[0] = (short)f2bf(lo[0]); bv[1] = (short)f2bf(lo[1]);
      bv[2] = (short)f2bf(lo[2]); bv[3] = (short)f2bf(lo[3]);
      bv[4] = (short)f2bf(hi[0]); bv[5] = (short)f2bf(hi[1]);
      bv[6] = (short)f2bf(hi[2]); bv[7] = (short)f2bf(hi[3]);
      bfrag[kt][rt] = bv;
    }
  }

  for (int nbi = 0; nbi < 8; ++nbi) {
    int nblk = (blockIdx.y * 8 + nbi) * 64;
    f32x4 acc[4][4];
#pragma unroll
    for (int a = 0; a < 4; ++a)
#pragma unroll
      for (int b = 0; b < 4; ++b) acc[a][b] = f32x4{0.f, 0.f, 0.f, 0.f};

#pragma unroll
    for (int kt = 0; kt < 8; ++kt) {
      int k0 = kt * 32 + q * 8;
      bf16x8 afrag[4];
#pragma unroll
      for (int mt = 0; mt < 4; ++mt)
        afrag[mt] = *(const bf16x8*)(WxT + (size_t)(nblk + mt * 16 + cl) * 256 + k0);
#pragma unroll
      for (int mt = 0; mt < 4; ++mt)
#pragma unroll
        for (int rt = 0; rt < 4; ++rt)
          acc[mt][rt] = __builtin_amdgcn_mfma_f32_16x16x32_bf16(
              afrag[mt], bfrag[kt][rt], acc[mt][rt], 0, 0, 0);
    }
#pragma unroll
    for (int mt = 0; mt < 4; ++mt) {
#pragma unroll
      for (int reg = 0; reg < 4; ++reg) {
        int n = nblk + mt * 16 + q * 4 + reg;
        float bb = bcat[n];
#pragma unroll
        for (int rt = 0; rt < 4; ++rt) {
          int rg16 = w * 4 + rt;  // = r>>4
          P[(((size_t)t * 16 + rg16) * 1024 + n) * 16 + cl] = f2bf(acc[mt][rt][reg] + bb);
        }
      }
    }
  }
}

// ---------- recurrent v16: 128 WGs x 2 rows, 1 cell/thread ----------
__global__ __launch_bounds__(512, 2) void lstm_recurrent(
    const unsigned short* __restrict__ WhT,
    const unsigned short* __restrict__ P,
    float* __restrict__ out) {
  // o-gate B-frags: [wave][block][kt][lane] bf16x8 = 128 KB (v5-proven layout)
  __shared__ bf16x8 o_w[8][2][8][64];
  // h double buffer, XOR-swizzled: byte ^= ((row&7)<<4).  16 KB.
  // Rows 0..1 live; rows 2..15 stay zero forever (A-tile zero-padding).
  __shared__ unsigned short hbuf[2][16 * 256];

  int tid = threadIdx.x;
  int w = tid >> 6, lane = tid & 63, q = lane >> 4, cl = lane & 15;
  int x = blockIdx.x;           // rows [2x, 2x+2)
  int rg16 = x >> 3;            // P row-group (global row >> 4)
  int idxb = (x & 7) * 2;       // P idx15 base for this WG's rows

  // ---- stage o-gate tiles into LDS: 8192 16B-chunks, 16 per thread
  for (int i = 0; i < 16; ++i) {
    int idx = tid + i * 512;
    int sw = idx >> 10, sb = (idx >> 9) & 1, skt = (idx >> 6) & 7, sl = idx & 63;
    int sq = sl >> 4, scl = sl & 15;
    int col = (2 * sw + sb) * 16 + scl;
    int k0 = skt * 32 + sq * 8;
    o_w[sw][sb][skt][sl] = *(const bf16x8*)(WhT + (size_t)(3 * 256 + col) * 256 + k0);
  }

  // ---- i,f,g gate tiles into VGPRs (static indexing only -- rule #20)
  bf16x8 wreg[2][3][8];  // [block][gate][kt] = 48 frags
#pragma unroll
  for (int b = 0; b < 2; ++b)
#pragma unroll
    for (int g = 0; g < 3; ++g)
#pragma unroll
      for (int kt = 0; kt < 8; ++kt) {
        int col = (2 * w + b) * 16 + cl;
        wreg[b][g][kt] =
            *(const bf16x8*)(WhT + (size_t)(g * 256 + col) * 256 + kt * 32 + q * 8);
      }

  // ---- zero BOTH h buffers (rows 2..15 never written; h_0 = 0)
  for (int i = tid; i < 4096; i += 512) ((unsigned int*)&hbuf[0][0])[i] = 0;

  // Memory clobber (v15-proven): rematerializing the wreg global loads
  // across this fence is illegal => weight values stay register-resident.
  asm volatile("" ::: "memory");
  __syncthreads();

  // A-read base (t-independent): row = cl, k-offset q*16 within kt-block,
  // swizzled.  Per kt: byte = abase ^ (kt*64) (bit-disjoint, v12-proven).
  int abase = cl * 512 + ((q * 16) ^ ((cl & 7) << 4));

  // EW ownership: lane (q,cl) owns the single cell
  //   block bq = q>>1, local row rq = q&1, col = 32w + bq*16 + cl.
  int bq = q >> 1, rq = q & 1;
  int colq = 32 * w + bq * 16 + cl;
  int idx15 = idxb + rq;

  float creg = 0.f;

  for (int t = 0; t < STEPS; ++t) {
    int rb = t & 1;
    bool lastt = (t == STEPS - 1);
    const unsigned short* hr = &hbuf[rb][0];
    unsigned short* hw = &hbuf[rb ^ 1][0];

    // P loads for this lane's cell: issued at step start, consumed after
    // the MFMA phase (~800cy later) -> L2/HBM latency stays hidden.
    unsigned short pv[4];
    {
      const unsigned short* pp =
          P + (((size_t)t * 16 + rg16) * 1024 + colq) * 16 + idx15;
#pragma unroll
      for (int g = 0; g < 4; ++g) pv[g] = pp[(size_t)g * 4096];
    }

    // ---- MFMA: af loaded once per kt, feeds both blocks x 4 gates
    f32x4 acc[2][4];
#pragma unroll
    for (int b = 0; b < 2; ++b)
#pragma unroll
      for (int g = 0; g < 4; ++g) acc[b][g] = f32x4{0.f, 0.f, 0.f, 0.f};

#pragma unroll
    for (int kt = 0; kt < 8; ++kt) {
      bf16x8 af = *(const bf16x8*)(hr + ((abase ^ (kt * 64)) >> 1));
      acc[0][0] = __builtin_amdgcn_mfma_f32_16x16x32_bf16(af, wreg[0][0][kt], acc[0][0], 0, 0, 0);
      acc[0][1] = __builtin_amdgcn_mfma_f32_16x16x32_bf16(af, wreg[0][1][kt], acc[0][1], 0, 0, 0);
      acc[0][2] = __builtin_amdgcn_mfma_f32_16x16x32_bf16(af, wreg[0][2][kt], acc[0][2], 0, 0, 0);
      acc[0][3] = __builtin_amdgcn_mfma_f32_16x16x32_bf16(af, o_w[w][0][kt][lane], acc[0][3], 0, 0, 0);
      acc[1][0] = __builtin_amdgcn_mfma_f32_16x16x32_bf16(af, wreg[1][0][kt], acc[1][0], 0, 0, 0);
      acc[1][1] = __builtin_amdgcn_mfma_f32_16x16x32_bf16(af, wreg[1][1][kt], acc[1][1], 0, 0, 0);
      acc[1][2] = __builtin_amdgcn_mfma_f32_16x16x32_bf16(af, wreg[1][2][kt], acc[1][2], 0, 0, 0);
      acc[1][3] = __builtin_amdgcn_mfma_f32_16x16x32_bf16(af, o_w[w][1][kt][lane], acc[1][3], 0, 0, 0);
    }

    // ---- redistribute: valid C rows {0,1} sit at q=0, e={0,1} (per block).
    // Target: lane (q,cl) gets (block q>>1, row q&1).
    float sh1[4], sh2[4], sh3[4], ag[4];
#pragma unroll
    for (int g = 0; g < 4; ++g) {
      sh1[g] = __shfl_xor(acc[0][g][1], 16, 64);  // q=1 <- q=0: b0 row1
      sh2[g] = __shfl_xor(acc[1][g][0], 32, 64);  // q=2 <- q=0: b1 row0
      sh3[g] = __shfl_xor(acc[1][g][1], 48, 64);  // q=3 <- q=0: b1 row1
    }
#pragma unroll
    for (int g = 0; g < 4; ++g)
      ag[g] = (q == 0) ? acc[0][g][0]
            : (q == 1) ? sh1[g]
            : (q == 2) ? sh2[g]
                       : sh3[g];

    // ---- EW: exactly one LSTM cell per lane.
    {
      float pi = ag[0] + bf2f(pv[0]);
      float pf = ag[1] + bf2f(pv[1]);
      float pg = ag[2] + bf2f(pv[2]);
      float po = ag[3] + bf2f(pv[3]);
      float ig = sig_f(pi), fg = sig_f(pf), gg = tanh_f(pg), og = sig_f(po);
      float cn = fg * creg + ig * gg;
      creg = cn;
      float hn = og * tanh_f(cn);
      if (!lastt) {
        int wb = rq * 512 + ((colq * 2) ^ (rq << 4));
        hw[wb >> 1] = f2bf(hn);
      } else {
        out[(size_t)(x * 2 + rq) * 256 + colq] = hn;
        out[65536 + (size_t)(x * 2 + rq) * 256 + colq] = cn;
      }
    }

    __syncthreads();  // h(t+1) complete before step t+1 reads it
  }
}

extern "C" void kernel_launch(void* const* d_in, const int* in_sizes, int n_in,
                              void* d_out, int out_size, void* d_ws, size_t ws_size,
                              hipStream_t stream) {
  const float* x = (const float*)d_in[0];
  const float* wx0 = (const float*)d_in[1];
  const float* wx1 = (const float*)d_in[5];
  const float* wx2 = (const float*)d_in[9];
  const float* wx3 = (const float*)d_in[13];
  const float* wh0 = (const float*)d_in[3];
  const float* wh1 = (const float*)d_in[7];
  const float* wh2 = (const float*)d_in[11];
  const float* wh3 = (const float*)d_in[15];
  const float* bx0 = (const float*)d_in[2];
  const float* bx1 = (const float*)d_in[6];
  const float* bx2 = (const float*)d_in[10];
  const float* bx3 = (const float*)d_in[14];
  const float* bh0 = (const float*)d_in[4];
  const float* bh1 = (const float*)d_in[8];
  const float* bh2 = (const float*)d_in[12];
  const float* bh3 = (const float*)d_in[16];

  char* ws = (char*)d_ws;
  unsigned short* WxT = (unsigned short*)(ws + 0);          // dead after precompute
  unsigned short* WhT = (unsigned short*)(ws + 524288);
  float* bcat = (float*)(ws + 1048576);
  unsigned short* P = (unsigned short*)(ws + 1052672);      // [t][rg16][n][16] bf16

  lstm_prep_w<<<dim3(8, 8, 8), 256, 0, stream>>>(wx0, wx1, wx2, wx3,
                                                 wh0, wh1, wh2, wh3, WxT, WhT);
  lstm_prep_b<<<4, 256, 0, stream>>>(bx0, bx1, bx2, bx3, bh0, bh1, bh2, bh3, bcat);
  lstm_precompute<<<dim3(255, 2), 256, 0, stream>>>(x, WxT, bcat, P);
  lstm_recurrent<<<dim3(128), 512, 0, stream>>>(WhT, P, (float*)d_out);
}

// Round 8
// 821.969 us; speedup vs baseline: 2.0695x; 1.0100x over previous
//
#include <hip/hip_runtime.h>

// LSTM_77893526880768: B=T=F=H=256.  256 independent row-chains, 255 steps.
//
// v17 = v16 + XCD-aware block swizzle to kill P line duplication.
//
// Evidence ladder:
//   v9 4.78us/step | v12 5.24 | v14 4.42 | v15 2.85 (weights pinned) |
//   v16 2.35 (128 WGs x 2 rows, 1 cell/thread).
//   Clock FIXED ~750 MHz (4x independent MFMA-cycle checks; heaters don't
//   move it).  v16 counters: FETCH_SIZE 525 MB (P=133 MB duplicated ~3.9x),
//   hbm_bytes/dur == 900 GB/s == dur -> FETCH-BOUND.  Root cause: the 8 WGs
//   sharing each P line (same x>>3, idx15 pairs 0..15 of the [16] inner dim)
//   land on 8 DIFFERENT XCDs under XCD = block_id % 8 (consecutive x), so
//   each line is fetched into up to 8 L2s (L3 absorbs some -> 3.9x).
//
// v17: remap x = (b&7)*16 + (b>>3).  Group y = x>>3 (the 8 WGs sharing P
//   lines) then has constant b%8 = floor(y/2) -> ONE XCD -> each P line
//   fetched once.  P traffic 525 -> 133 MB; WhT ~4 MB (16 WGs/XCD share L2).
//   Bijective on 0..127; rows written depend only on x -> semantics
//   unchanged; placement-independent correctness (no cross-WG comm).
//   Everything else byte-identical to v16.
//
// Workspace layout:
//   [0, 512K)       WxT bf16   (dead after precompute)
//   [512K, 1M)      WhT bf16
//   [1M, 1M+4K)     bcat fp32
//   [1M+4K, ...)    P bf16  [t][rg16][n][16] = 133,693,440 B

#define STEPS 255

typedef short bf16x8 __attribute__((ext_vector_type(8)));
typedef short bf16x4 __attribute__((ext_vector_type(4)));
typedef float f32x4  __attribute__((ext_vector_type(4)));

__device__ inline unsigned short f2bf(float f) {
  unsigned int u = __float_as_uint(f);
  unsigned int r = (u + 0x7FFFu + ((u >> 16) & 1u)) >> 16;  // RNE
  return (unsigned short)r;
}
__device__ inline float bf2f(unsigned short s) {
  return __uint_as_float(((unsigned int)s) << 16);
}
__device__ inline float sig_f(float x) {
  float e = exp2f(-1.442695041f * x);
  return __builtin_amdgcn_rcpf(1.0f + e);
}
__device__ inline float tanh_f(float x) {
  float e = exp2f(-2.885390082f * x);
  return 2.0f * __builtin_amdgcn_rcpf(1.0f + e) - 1.0f;
}

// ---------- prep: W transpose (W[k][j] fp32 -> WT[g*256+j][k] bf16) ----------
__global__ __launch_bounds__(256) void lstm_prep_w(
    const float* __restrict__ m0, const float* __restrict__ m1,
    const float* __restrict__ m2, const float* __restrict__ m3,
    const float* __restrict__ m4, const float* __restrict__ m5,
    const float* __restrict__ m6, const float* __restrict__ m7,
    unsigned short* __restrict__ WxT, unsigned short* __restrict__ WhT) {
  const float* mats[8] = {m0, m1, m2, m3, m4, m5, m6, m7};
  int mat = blockIdx.z;
  const float* W = mats[mat];
  unsigned short* out = (mat < 4 ? WxT : WhT) + (size_t)(mat & 3) * 256 * 256;
  int kblk = blockIdx.x * 32, jblk = blockIdx.y * 32;
  __shared__ float tile[32][33];
  int tx = threadIdx.x & 31, ty = threadIdx.x >> 5;
#pragma unroll
  for (int i = 0; i < 4; ++i) {
    int kk = ty + i * 8;
    tile[kk][tx] = W[(size_t)(kblk + kk) * 256 + jblk + tx];
  }
  __syncthreads();
#pragma unroll
  for (int i = 0; i < 4; ++i) {
    int jj = ty + i * 8;
    out[(size_t)(jblk + jj) * 256 + kblk + tx] = f2bf(tile[tx][jj]);
  }
}

// ---------- prep: bias fold ----------
__global__ void lstm_prep_b(
    const float* __restrict__ bx0, const float* __restrict__ bx1,
    const float* __restrict__ bx2, const float* __restrict__ bx3,
    const float* __restrict__ bh0, const float* __restrict__ bh1,
    const float* __restrict__ bh2, const float* __restrict__ bh3,
    float* __restrict__ bcat) {
  const float* bx[4] = {bx0, bx1, bx2, bx3};
  const float* bh[4] = {bh0, bh1, bh2, bh3};
  int i = blockIdx.x * 256 + threadIdx.x;
  int g = i >> 8, j = i & 255;
  bcat[i] = bx[g][j] + bh[g][j];
}

// ---------- precompute: P[t][rg16][n][rl] = bcat[n] + sum_k x[r,t,k] Wx[k,n] ----------
// grid (255, 2): blockIdx.y selects 8 of the 16 n-blocks (x-frags duplicated).
__global__ __launch_bounds__(256, 1) void lstm_precompute(
    const float* __restrict__ x, const unsigned short* __restrict__ WxT,
    const float* __restrict__ bcat, unsigned short* __restrict__ P) {
  int t = blockIdx.x;
  int tid = threadIdx.x;
  int w = tid >> 6, lane = tid & 63, q = lane >> 4, cl = lane & 15;
  int rbase = w * 64;

  bf16x8 bfrag[8][4];
#pragma unroll
  for (int kt = 0; kt < 8; ++kt) {
    int k0 = kt * 32 + q * 8;
#pragma unroll
    for (int rt = 0; rt < 4; ++rt) {
      const float* xp = x + (((size_t)(rbase + rt * 16 + cl) * 256 + t) * 256 + k0);
      f32x4 lo = *(const f32x4*)xp;
      f32x4 hi = *(const f32x4*)(xp + 4);
      bf16x8 bv;
      bv[0] = (short)f2bf(lo[0]); bv[1] = (short)f2bf(lo[1]);
      bv[2] = (short)f2bf(lo[2]); bv[3] = (short)f2bf(lo[3]);
      bv[4] = (short)f2bf(hi[0]); bv[5] = (short)f2bf(hi[1]);
      bv[6] = (short)f2bf(hi[2]); bv[7] = (short)f2bf(hi[3]);
      bfrag[kt][rt] = bv;
    }
  }

  for (int nbi = 0; nbi < 8; ++nbi) {
    int nblk = (blockIdx.y * 8 + nbi) * 64;
    f32x4 acc[4][4];
#pragma unroll
    for (int a = 0; a < 4; ++a)
#pragma unroll
      for (int b = 0; b < 4; ++b) acc[a][b] = f32x4{0.f, 0.f, 0.f, 0.f};

#pragma unroll
    for (int kt = 0; kt < 8; ++kt) {
      int k0 = kt * 32 + q * 8;
      bf16x8 afrag[4];
#pragma unroll
      for (int mt = 0; mt < 4; ++mt)
        afrag[mt] = *(const bf16x8*)(WxT + (size_t)(nblk + mt * 16 + cl) * 256 + k0);
#pragma unroll
      for (int mt = 0; mt < 4; ++mt)
#pragma unroll
        for (int rt = 0; rt < 4; ++rt)
          acc[mt][rt] = __builtin_amdgcn_mfma_f32_16x16x32_bf16(
              afrag[mt], bfrag[kt][rt], acc[mt][rt], 0, 0, 0);
    }
#pragma unroll
    for (int mt = 0; mt < 4; ++mt) {
#pragma unroll
      for (int reg = 0; reg < 4; ++reg) {
        int n = nblk + mt * 16 + q * 4 + reg;
        float bb = bcat[n];
#pragma unroll
        for (int rt = 0; rt < 4; ++rt) {
          int rg16 = w * 4 + rt;  // = r>>4
          P[(((size_t)t * 16 + rg16) * 1024 + n) * 16 + cl] = f2bf(acc[mt][rt][reg] + bb);
        }
      }
    }
  }
}

// ---------- recurrent v17: 128 WGs x 2 rows, XCD-swizzled block index ----------
__global__ __launch_bounds__(512, 2) void lstm_recurrent(
    const unsigned short* __restrict__ WhT,
    const unsigned short* __restrict__ P,
    float* __restrict__ out) {
  // o-gate B-frags: [wave][block][kt][lane] bf16x8 = 128 KB (v5-proven layout)
  __shared__ bf16x8 o_w[8][2][8][64];
  // h double buffer, XOR-swizzled: byte ^= ((row&7)<<4).  16 KB.
  // Rows 0..1 live; rows 2..15 stay zero forever (A-tile zero-padding).
  __shared__ unsigned short hbuf[2][16 * 256];

  int tid = threadIdx.x;
  int w = tid >> 6, lane = tid & 63, q = lane >> 4, cl = lane & 15;
  // XCD swizzle (v17): the 8 WGs sharing P lines (same x>>3) get identical
  // b%8 -> one XCD -> each P line fetched into exactly one L2.
  int b_ = blockIdx.x;
  int x = (b_ & 7) * 16 + (b_ >> 3);  // bijective 0..127
  int rg16 = x >> 3;            // P row-group (global row >> 4)
  int idxb = (x & 7) * 2;       // P idx15 base for this WG's rows

  // ---- stage o-gate tiles into LDS: 8192 16B-chunks, 16 per thread
  for (int i = 0; i < 16; ++i) {
    int idx = tid + i * 512;
    int sw = idx >> 10, sb = (idx >> 9) & 1, skt = (idx >> 6) & 7, sl = idx & 63;
    int sq = sl >> 4, scl = sl & 15;
    int col = (2 * sw + sb) * 16 + scl;
    int k0 = skt * 32 + sq * 8;
    o_w[sw][sb][skt][sl] = *(const bf16x8*)(WhT + (size_t)(3 * 256 + col) * 256 + k0);
  }

  // ---- i,f,g gate tiles into VGPRs (static indexing only -- rule #20)
  bf16x8 wreg[2][3][8];  // [block][gate][kt] = 48 frags
#pragma unroll
  for (int b = 0; b < 2; ++b)
#pragma unroll
    for (int g = 0; g < 3; ++g)
#pragma unroll
      for (int kt = 0; kt < 8; ++kt) {
        int col = (2 * w + b) * 16 + cl;
        wreg[b][g][kt] =
            *(const bf16x8*)(WhT + (size_t)(g * 256 + col) * 256 + kt * 32 + q * 8);
      }

  // ---- zero BOTH h buffers (rows 2..15 never written; h_0 = 0)
  for (int i = tid; i < 4096; i += 512) ((unsigned int*)&hbuf[0][0])[i] = 0;

  // Memory clobber (v15-proven): rematerializing the wreg global loads
  // across this fence is illegal => weight values stay register-resident.
  asm volatile("" ::: "memory");
  __syncthreads();

  // A-read base (t-independent): row = cl, k-offset q*16 within kt-block,
  // swizzled.  Per kt: byte = abase ^ (kt*64) (bit-disjoint, v12-proven).
  int abase = cl * 512 + ((q * 16) ^ ((cl & 7) << 4));

  // EW ownership: lane (q,cl) owns the single cell
  //   block bq = q>>1, local row rq = q&1, col = 32w + bq*16 + cl.
  int bq = q >> 1, rq = q & 1;
  int colq = 32 * w + bq * 16 + cl;
  int idx15 = idxb + rq;

  float creg = 0.f;

  for (int t = 0; t < STEPS; ++t) {
    int rb = t & 1;
    bool lastt = (t == STEPS - 1);
    const unsigned short* hr = &hbuf[rb][0];
    unsigned short* hw = &hbuf[rb ^ 1][0];

    // P loads for this lane's cell: issued at step start, consumed after
    // the MFMA phase (~800cy later) -> L2/HBM latency stays hidden.
    unsigned short pv[4];
    {
      const unsigned short* pp =
          P + (((size_t)t * 16 + rg16) * 1024 + colq) * 16 + idx15;
#pragma unroll
      for (int g = 0; g < 4; ++g) pv[g] = pp[(size_t)g * 4096];
    }

    // ---- MFMA: af loaded once per kt, feeds both blocks x 4 gates
    f32x4 acc[2][4];
#pragma unroll
    for (int b = 0; b < 2; ++b)
#pragma unroll
      for (int g = 0; g < 4; ++g) acc[b][g] = f32x4{0.f, 0.f, 0.f, 0.f};

#pragma unroll
    for (int kt = 0; kt < 8; ++kt) {
      bf16x8 af = *(const bf16x8*)(hr + ((abase ^ (kt * 64)) >> 1));
      acc[0][0] = __builtin_amdgcn_mfma_f32_16x16x32_bf16(af, wreg[0][0][kt], acc[0][0], 0, 0, 0);
      acc[0][1] = __builtin_amdgcn_mfma_f32_16x16x32_bf16(af, wreg[0][1][kt], acc[0][1], 0, 0, 0);
      acc[0][2] = __builtin_amdgcn_mfma_f32_16x16x32_bf16(af, wreg[0][2][kt], acc[0][2], 0, 0, 0);
      acc[0][3] = __builtin_amdgcn_mfma_f32_16x16x32_bf16(af, o_w[w][0][kt][lane], acc[0][3], 0, 0, 0);
      acc[1][0] = __builtin_amdgcn_mfma_f32_16x16x32_bf16(af, wreg[1][0][kt], acc[1][0], 0, 0, 0);
      acc[1][1] = __builtin_amdgcn_mfma_f32_16x16x32_bf16(af, wreg[1][1][kt], acc[1][1], 0, 0, 0);
      acc[1][2] = __builtin_amdgcn_mfma_f32_16x16x32_bf16(af, wreg[1][2][kt], acc[1][2], 0, 0, 0);
      acc[1][3] = __builtin_amdgcn_mfma_f32_16x16x32_bf16(af, o_w[w][1][kt][lane], acc[1][3], 0, 0, 0);
    }

    // ---- redistribute: valid C rows {0,1} sit at q=0, e={0,1} (per block).
    // Target: lane (q,cl) gets (block q>>1, row q&1).
    float sh1[4], sh2[4], sh3[4], ag[4];
#pragma unroll
    for (int g = 0; g < 4; ++g) {
      sh1[g] = __shfl_xor(acc[0][g][1], 16, 64);  // q=1 <- q=0: b0 row1
      sh2[g] = __shfl_xor(acc[1][g][0], 32, 64);  // q=2 <- q=0: b1 row0
      sh3[g] = __shfl_xor(acc[1][g][1], 48, 64);  // q=3 <- q=0: b1 row1
    }
#pragma unroll
    for (int g = 0; g < 4; ++g)
      ag[g] = (q == 0) ? acc[0][g][0]
            : (q == 1) ? sh1[g]
            : (q == 2) ? sh2[g]
                       : sh3[g];

    // ---- EW: exactly one LSTM cell per lane.
    {
      float pi = ag[0] + bf2f(pv[0]);
      float pf = ag[1] + bf2f(pv[1]);
      float pg = ag[2] + bf2f(pv[2]);
      float po = ag[3] + bf2f(pv[3]);
      float ig = sig_f(pi), fg = sig_f(pf), gg = tanh_f(pg), og = sig_f(po);
      float cn = fg * creg + ig * gg;
      creg = cn;
      float hn = og * tanh_f(cn);
      if (!lastt) {
        int wb = rq * 512 + ((colq * 2) ^ (rq << 4));
        hw[wb >> 1] = f2bf(hn);
      } else {
        out[(size_t)(x * 2 + rq) * 256 + colq] = hn;
        out[65536 + (size_t)(x * 2 + rq) * 256 + colq] = cn;
      }
    }

    __syncthreads();  // h(t+1) complete before step t+1 reads it
  }
}

extern "C" void kernel_launch(void* const* d_in, const int* in_sizes, int n_in,
                              void* d_out, int out_size, void* d_ws, size_t ws_size,
                              hipStream_t stream) {
  const float* x = (const float*)d_in[0];
  const float* wx0 = (const float*)d_in[1];
  const float* wx1 = (const float*)d_in[5];
  const float* wx2 = (const float*)d_in[9];
  const float* wx3 = (const float*)d_in[13];
  const float* wh0 = (const float*)d_in[3];
  const float* wh1 = (const float*)d_in[7];
  const float* wh2 = (const float*)d_in[11];
  const float* wh3 = (const float*)d_in[15];
  const float* bx0 = (const float*)d_in[2];
  const float* bx1 = (const float*)d_in[6];
  const float* bx2 = (const float*)d_in[10];
  const float* bx3 = (const float*)d_in[14];
  const float* bh0 = (const float*)d_in[4];
  const float* bh1 = (const float*)d_in[8];
  const float* bh2 = (const float*)d_in[12];
  const float* bh3 = (const float*)d_in[16];

  char* ws = (char*)d_ws;
  unsigned short* WxT = (unsigned short*)(ws + 0);          // dead after precompute
  unsigned short* WhT = (unsigned short*)(ws + 524288);
  float* bcat = (float*)(ws + 1048576);
  unsigned short* P = (unsigned short*)(ws + 1052672);      // [t][rg16][n][16] bf16

  lstm_prep_w<<<dim3(8, 8, 8), 256, 0, stream>>>(wx0, wx1, wx2, wx3,
                                                 wh0, wh1, wh2, wh3, WxT, WhT);
  lstm_prep_b<<<4, 256, 0, stream>>>(bx0, bx1, bx2, bx3, bh0, bh1, bh2, bh3, bcat);
  lstm_precompute<<<dim3(255, 2), 256, 0, stream>>>(x, WxT, bcat, P);
  lstm_recurrent<<<dim3(128), 512, 0, stream>>>(WhT, P, (float*)d_out);
}